// Round 2
// baseline (59.385 us; speedup 1.0000x reference)
//
#include <hip/hip_runtime.h>
#include <hip/hip_bf16.h>

// RoI pooling (ROI-Align bilinear, A=7) on NHWC fp32 feature map.
// features_map: (1, 128, 128, 256) fp32
// boxes:        (2000, 4) int32  [x1, y1, x2, y2]
// out:          (2000, 1, 7, 7, 256) fp32
//
// One 64-lane wave per sample point (box, py, px); each lane handles 4
// consecutive channels via float4 -> 64*16B = 1KB coalesced loads/stores.

#define FM_H 128
#define FM_W 128
#define FM_C 256
#define ANCH 7

__global__ __launch_bounds__(256) void roi_pool_kernel(
    const float* __restrict__ fm,
    const int* __restrict__ boxes,
    float* __restrict__ out,
    int n_samples)  // N * ANCH * ANCH
{
    const int gtid = blockIdx.x * blockDim.x + threadIdx.x;
    const int wave = gtid >> 6;          // one wave per sample point
    const int lane = threadIdx.x & 63;
    if (wave >= n_samples) return;

    const int box = wave / (ANCH * ANCH);
    const int s   = wave - box * (ANCH * ANCH);
    const int py  = s / ANCH;
    const int px  = s - py * ANCH;

    const int x1 = boxes[box * 4 + 0];
    const int y1 = boxes[box * 4 + 1];
    const int x2 = boxes[box * 4 + 2];
    const int y2 = boxes[box * 4 + 3];

    // ---- axis_samples(y1, y2) at index py ----
    const float spany = (float)(y2 - y1);
    float sy = ((float)py + 0.5f) * (spany / (float)ANCH) - 0.5f;
    sy = fminf(fmaxf(sy, 0.0f), fmaxf(spany - 1.0f, 0.0f));
    const int iy0 = (int)floorf(sy);
    const int iy1 = min(iy0 + 1, y2 - y1 - 1);
    const float fy = sy - (float)iy0;
    const int ys0 = iy0 + y1;
    const int ys1 = iy1 + y1;

    // ---- axis_samples(x1, x2) at index px ----
    const float spanx = (float)(x2 - x1);
    float sx = ((float)px + 0.5f) * (spanx / (float)ANCH) - 0.5f;
    sx = fminf(fmaxf(sx, 0.0f), fmaxf(spanx - 1.0f, 0.0f));
    const int ix0 = (int)floorf(sx);
    const int ix1 = min(ix0 + 1, x2 - x1 - 1);
    const float fx = sx - (float)ix0;
    const int xs0 = ix0 + x1;
    const int xs1 = ix1 + x1;

    const float4* p00 = (const float4*)(fm + ((size_t)ys0 * FM_W + xs0) * FM_C);
    const float4* p01 = (const float4*)(fm + ((size_t)ys0 * FM_W + xs1) * FM_C);
    const float4* p10 = (const float4*)(fm + ((size_t)ys1 * FM_W + xs0) * FM_C);
    const float4* p11 = (const float4*)(fm + ((size_t)ys1 * FM_W + xs1) * FM_C);

    const float4 v00 = p00[lane];
    const float4 v01 = p01[lane];
    const float4 v10 = p10[lane];
    const float4 v11 = p11[lane];

    const float gx = 1.0f - fx;
    const float gy = 1.0f - fy;

    // Match reference order: top = v00*(1-fx)+v01*fx; bot = ...; r = top*(1-fy)+bot*fy
    float4 r;
    {
        float top = v00.x * gx + v01.x * fx;
        float bot = v10.x * gx + v11.x * fx;
        r.x = top * gy + bot * fy;
    }
    {
        float top = v00.y * gx + v01.y * fx;
        float bot = v10.y * gx + v11.y * fx;
        r.y = top * gy + bot * fy;
    }
    {
        float top = v00.z * gx + v01.z * fx;
        float bot = v10.z * gx + v11.z * fx;
        r.z = top * gy + bot * fy;
    }
    {
        float top = v00.w * gx + v01.w * fx;
        float bot = v10.w * gx + v11.w * fx;
        r.w = top * gy + bot * fy;
    }

    float4* dst = (float4*)(out + (size_t)wave * FM_C);
    dst[lane] = r;
}

extern "C" void kernel_launch(void* const* d_in, const int* in_sizes, int n_in,
                              void* d_out, int out_size, void* d_ws, size_t ws_size,
                              hipStream_t stream) {
    const float* fm    = (const float*)d_in[0];   // (1,128,128,256) fp32
    const int*   boxes = (const int*)d_in[1];     // (N,4) int32
    // d_in[2] = anchor_size scalar (7); layout constants hard-coded to setup.

    const int N = in_sizes[1] / 4;
    const int n_samples = N * ANCH * ANCH;

    float* out = (float*)d_out;

    const int threads = 256;                       // 4 waves per block
    const int waves_per_block = threads / 64;
    const int grid = (n_samples + waves_per_block - 1) / waves_per_block;

    roi_pool_kernel<<<grid, threads, 0, stream>>>(fm, boxes, out, n_samples);
}

// Round 6
// 52.196 us; speedup vs baseline: 1.1377x; 1.1377x over previous
//
#include <hip/hip_runtime.h>
#include <hip/hip_bf16.h>

// RoI pooling (ROI-Align bilinear, A=7) on NHWC fp32 feature map.
// features_map: (1, 128, 128, 256) fp32
// boxes:        (2000, 4) int32  [x1, y1, x2, y2]
// out:          (2000, 1, 7, 7, 256) fp32
//
// One 64-lane wave per sample point (box, py, px); each lane handles 4
// consecutive channels via float4 -> 64*16B = 1KB coalesced loads/stores.
//
// Round-4 = round-3 with the nontemporal-store compile fix (native clang
// ext_vector float4 instead of HIP_vector_type):
//  - chunked bijective XCD swizzle on blockIdx (m204 formula)
//  - nontemporal output stores (100 MB streaming write never re-read)
//  - readfirstlane on sample id: box math + boxes[] loads on scalar pipe.

#define FM_H 128
#define FM_W 128
#define FM_C 256
#define ANCH 7

typedef float f4 __attribute__((ext_vector_type(4)));

__global__ __launch_bounds__(256) void roi_pool_kernel(
    const float* __restrict__ fm,
    const int* __restrict__ boxes,
    float* __restrict__ out,
    int n_samples)  // N * ANCH * ANCH
{
    // ---- bijective chunked XCD swizzle (blocks dispatch round-robin over
    // 8 XCDs; give XCD k a contiguous block range so concurrent blocks on
    // one XCD process neighboring samples) ----
    const int nb  = gridDim.x;
    const int b   = blockIdx.x;
    const int q   = nb >> 3;
    const int r   = nb & 7;
    const int xcd = b & 7;
    const int idx = b >> 3;
    const int sb  = (xcd < r ? xcd * (q + 1) : r * (q + 1) + (xcd - r) * q) + idx;

    const int lane = threadIdx.x & 63;
    // sample id, forced wave-uniform onto the scalar pipe
    const int wave = __builtin_amdgcn_readfirstlane((sb << 2) + (threadIdx.x >> 6));
    if (wave >= n_samples) return;

    const int box = wave / (ANCH * ANCH);
    const int s   = wave - box * (ANCH * ANCH);
    const int py  = s / ANCH;
    const int px  = s - py * ANCH;

    const int x1 = boxes[box * 4 + 0];
    const int y1 = boxes[box * 4 + 1];
    const int x2 = boxes[box * 4 + 2];
    const int y2 = boxes[box * 4 + 3];

    // ---- axis_samples(y1, y2) at index py ----
    const float spany = (float)(y2 - y1);
    float sy = ((float)py + 0.5f) * (spany / (float)ANCH) - 0.5f;
    sy = fminf(fmaxf(sy, 0.0f), fmaxf(spany - 1.0f, 0.0f));
    const int iy0 = (int)floorf(sy);
    const int iy1 = min(iy0 + 1, y2 - y1 - 1);
    const float fy = sy - (float)iy0;
    const int ys0 = iy0 + y1;
    const int ys1 = iy1 + y1;

    // ---- axis_samples(x1, x2) at index px ----
    const float spanx = (float)(x2 - x1);
    float sx = ((float)px + 0.5f) * (spanx / (float)ANCH) - 0.5f;
    sx = fminf(fmaxf(sx, 0.0f), fmaxf(spanx - 1.0f, 0.0f));
    const int ix0 = (int)floorf(sx);
    const int ix1 = min(ix0 + 1, x2 - x1 - 1);
    const float fx = sx - (float)ix0;
    const int xs0 = ix0 + x1;
    const int xs1 = ix1 + x1;

    const f4* p00 = (const f4*)(fm + ((size_t)ys0 * FM_W + xs0) * FM_C);
    const f4* p01 = (const f4*)(fm + ((size_t)ys0 * FM_W + xs1) * FM_C);
    const f4* p10 = (const f4*)(fm + ((size_t)ys1 * FM_W + xs0) * FM_C);
    const f4* p11 = (const f4*)(fm + ((size_t)ys1 * FM_W + xs1) * FM_C);

    const f4 v00 = p00[lane];
    const f4 v01 = p01[lane];
    const f4 v10 = p10[lane];
    const f4 v11 = p11[lane];

    const float gx = 1.0f - fx;
    const float gy = 1.0f - fy;

    // Match reference order: top = v00*(1-fx)+v01*fx; bot = ...; r = top*(1-fy)+bot*fy
    f4 res;
    #pragma unroll
    for (int j = 0; j < 4; ++j) {
        float top = v00[j] * gx + v01[j] * fx;
        float bot = v10[j] * gx + v11[j] * fx;
        res[j] = top * gy + bot * fy;
    }

    f4* dst = (f4*)(out + (size_t)wave * FM_C);
    __builtin_nontemporal_store(res, &dst[lane]);
}

extern "C" void kernel_launch(void* const* d_in, const int* in_sizes, int n_in,
                              void* d_out, int out_size, void* d_ws, size_t ws_size,
                              hipStream_t stream) {
    const float* fm    = (const float*)d_in[0];   // (1,128,128,256) fp32
    const int*   boxes = (const int*)d_in[1];     // (N,4) int32
    // d_in[2] = anchor_size scalar (7); layout constants hard-coded to setup.

    const int N = in_sizes[1] / 4;
    const int n_samples = N * ANCH * ANCH;

    float* out = (float*)d_out;

    const int threads = 256;                       // 4 waves per block
    const int waves_per_block = threads / 64;
    const int grid = (n_samples + waves_per_block - 1) / waves_per_block;

    roi_pool_kernel<<<grid, threads, 0, stream>>>(fm, boxes, out, n_samples);
}

// Round 7
// 34.379 us; speedup vs baseline: 1.7273x; 1.5182x over previous
//
#include <hip/hip_runtime.h>
#include <hip/hip_bf16.h>

// RoI pooling (ROI-Align bilinear, A=7) on NHWC fp32 feature map.
// features_map: (1, 128, 128, 256) fp32
// boxes:        (2000, 4) int32  [x1, y1, x2, y2]
// out:          (2000, 1, 7, 7, 256) fp32
//
// Round-7: spatial box sort for per-XCD L2 locality.
//  - Kernel 1 (1 block): counting-sort box indices by bucket
//    ((y1>>4)<<3 | (x1>>4)) into order[] in d_ws. Output position of each
//    box in d_out is unchanged (original index), so any intra-bucket
//    permutation yields identical output bytes.
//  - Kernel 2: one wave per sample; sorted-box indirection + chunked
//    bijective XCD swizzle => concurrently-running boxes on one XCD share
//    a narrow y-band of fm (~hot rows fit the 4 MiB per-XCD L2), turning
//    L3-bandwidth-bound gathers into L2 hits.
//  - nontemporal stores for the 100 MB streaming output.

#define FM_H 128
#define FM_W 128
#define FM_C 256
#define ANCH 7
#define NSAMP (ANCH * ANCH)

typedef float f4 __attribute__((ext_vector_type(4)));

__global__ __launch_bounds__(256) void sort_boxes_kernel(
    const int* __restrict__ boxes, int* __restrict__ order, int n_boxes)
{
    __shared__ int cursor[64];
    const int tid = threadIdx.x;
    if (tid < 64) cursor[tid] = 0;
    __syncthreads();

    // histogram
    for (int i = tid; i < n_boxes; i += 256) {
        const int x1 = boxes[i * 4 + 0];
        const int y1 = boxes[i * 4 + 1];
        const int key = ((y1 >> 4) << 3) | (x1 >> 4);
        atomicAdd(&cursor[key], 1);
    }
    __syncthreads();

    // exclusive prefix (serial over 64 entries; trivial)
    if (tid == 0) {
        int run = 0;
        for (int k = 0; k < 64; ++k) {
            int c = cursor[k];
            cursor[k] = run;
            run += c;
        }
    }
    __syncthreads();

    // scatter (intra-bucket order nondeterministic; output invariant to it)
    for (int i = tid; i < n_boxes; i += 256) {
        const int x1 = boxes[i * 4 + 0];
        const int y1 = boxes[i * 4 + 1];
        const int key = ((y1 >> 4) << 3) | (x1 >> 4);
        const int pos = atomicAdd(&cursor[key], 1);
        order[pos] = i;
    }
}

__global__ __launch_bounds__(256) void roi_pool_kernel(
    const float* __restrict__ fm,
    const int* __restrict__ boxes,
    const int* __restrict__ order,
    float* __restrict__ out,
    int n_samples)  // N * 49
{
    // chunked bijective XCD swizzle: XCD k gets a contiguous block range so
    // concurrent blocks on one XCD process spatially-neighboring boxes.
    const int nb  = gridDim.x;
    const int b   = blockIdx.x;
    const int q   = nb >> 3;
    const int r   = nb & 7;
    const int xcd = b & 7;
    const int idx = b >> 3;
    const int sb  = (xcd < r ? xcd * (q + 1) : r * (q + 1) + (xcd - r) * q) + idx;

    const int lane = threadIdx.x & 63;
    // sample id in sorted order, wave-uniform on the scalar pipe
    const int wave = __builtin_amdgcn_readfirstlane((sb << 2) + (threadIdx.x >> 6));
    if (wave >= n_samples) return;

    const int sorted_box = wave / NSAMP;
    const int s   = wave - sorted_box * NSAMP;
    const int py  = s / ANCH;
    const int px  = s - py * ANCH;
    const int box = order[sorted_box];          // original box index

    const int x1 = boxes[box * 4 + 0];
    const int y1 = boxes[box * 4 + 1];
    const int x2 = boxes[box * 4 + 2];
    const int y2 = boxes[box * 4 + 3];

    // ---- axis_samples(y1, y2) at index py ----
    const float spany = (float)(y2 - y1);
    float sy = ((float)py + 0.5f) * (spany / (float)ANCH) - 0.5f;
    sy = fminf(fmaxf(sy, 0.0f), fmaxf(spany - 1.0f, 0.0f));
    const int iy0 = (int)floorf(sy);
    const int iy1 = min(iy0 + 1, y2 - y1 - 1);
    const float fy = sy - (float)iy0;
    const int ys0 = iy0 + y1;
    const int ys1 = iy1 + y1;

    // ---- axis_samples(x1, x2) at index px ----
    const float spanx = (float)(x2 - x1);
    float sx = ((float)px + 0.5f) * (spanx / (float)ANCH) - 0.5f;
    sx = fminf(fmaxf(sx, 0.0f), fmaxf(spanx - 1.0f, 0.0f));
    const int ix0 = (int)floorf(sx);
    const int ix1 = min(ix0 + 1, x2 - x1 - 1);
    const float fx = sx - (float)ix0;
    const int xs0 = ix0 + x1;
    const int xs1 = ix1 + x1;

    const f4* p00 = (const f4*)(fm + ((size_t)ys0 * FM_W + xs0) * FM_C);
    const f4* p01 = (const f4*)(fm + ((size_t)ys0 * FM_W + xs1) * FM_C);
    const f4* p10 = (const f4*)(fm + ((size_t)ys1 * FM_W + xs0) * FM_C);
    const f4* p11 = (const f4*)(fm + ((size_t)ys1 * FM_W + xs1) * FM_C);

    const f4 v00 = p00[lane];
    const f4 v01 = p01[lane];
    const f4 v10 = p10[lane];
    const f4 v11 = p11[lane];

    const float gx = 1.0f - fx;
    const float gy = 1.0f - fy;

    // Match reference order: top = v00*(1-fx)+v01*fx; bot likewise; then y-lerp
    f4 res;
    #pragma unroll
    for (int j = 0; j < 4; ++j) {
        float top = v00[j] * gx + v01[j] * fx;
        float bot = v10[j] * gx + v11[j] * fx;
        res[j] = top * gy + bot * fy;
    }

    // write at ORIGINAL box position => output independent of sort order
    f4* dst = (f4*)(out + ((size_t)box * NSAMP + s) * FM_C);
    __builtin_nontemporal_store(res, &dst[lane]);
}

extern "C" void kernel_launch(void* const* d_in, const int* in_sizes, int n_in,
                              void* d_out, int out_size, void* d_ws, size_t ws_size,
                              hipStream_t stream) {
    const float* fm    = (const float*)d_in[0];   // (1,128,128,256) fp32
    const int*   boxes = (const int*)d_in[1];     // (N,4) int32
    // d_in[2] = anchor_size scalar (7); layout constants hard-coded to setup.

    const int N = in_sizes[1] / 4;
    const int n_samples = N * NSAMP;

    float* out  = (float*)d_out;
    int* order  = (int*)d_ws;                      // N ints of scratch

    sort_boxes_kernel<<<1, 256, 0, stream>>>(boxes, order, N);

    const int threads = 256;                       // 4 waves per block
    const int waves_per_block = threads / 64;
    const int grid = (n_samples + waves_per_block - 1) / waves_per_block;

    roi_pool_kernel<<<grid, threads, 0, stream>>>(fm, boxes, order, out, n_samples);
}